// Round 1
// baseline (1316.966 us; speedup 1.0000x reference)
//
#include <hip/hip_runtime.h>
#include <hip/hip_bf16.h>
#include <cstdint>

#define DEVINL __device__ __forceinline__

typedef unsigned short u16;
typedef short bf16x8 __attribute__((ext_vector_type(8)));
typedef float f32x4 __attribute__((ext_vector_type(4)));

// ---------- small helpers ----------
DEVINL u16 f2b(float f) {
    union { float f; uint32_t u; } x{f};
    uint32_t r = x.u + 0x7fffu + ((x.u >> 16) & 1u);   // RNE
    return (u16)(r >> 16);
}
DEVINL float b2f(u16 h) {
    union { uint32_t u; float f; } x{(uint32_t)h << 16};
    return x.f;
}
DEVINL float gelu_exact(float v) {
    return 0.5f * v * (1.0f + erff(v * 0.70710678118654752f));
}
// global -> LDS async DMA, 16B per lane. LDS dest must be wave-uniform base + lane*16.
DEVINL void gload_lds16(const void* g, void* l) {
    __builtin_amdgcn_global_load_lds(
        (const __attribute__((address_space(1))) void*)(uintptr_t)g,
        (__attribute__((address_space(3))) void*)(uint32_t)(uintptr_t)l,
        16, 0, 0);
}

// ---------- fp32 -> bf16 convert ----------
__global__ void f2b_kernel(const float* __restrict__ in, u16* __restrict__ out, int n) {
    int i = (blockIdx.x * 256 + threadIdx.x) * 8;
    if (i + 8 <= n) {
        float4 a = *(const float4*)(in + i);
        float4 b = *(const float4*)(in + i + 4);
        u16 t[8] = {f2b(a.x), f2b(a.y), f2b(a.z), f2b(a.w),
                    f2b(b.x), f2b(b.y), f2b(b.z), f2b(b.w)};
        *(uint4*)(out + i) = *(const uint4*)t;
    }
}

// ---------- per-(b,c) mean/std over L ----------
__global__ void stats_kernel(const float* __restrict__ xe, float* __restrict__ mean,
                             float* __restrict__ stdv) {
    int b = blockIdx.x, ln = threadIdx.x;          // 64 threads
    int c = ln & 15, part = ln >> 4;
    float s = 0.f, sq = 0.f;
    for (int l = part; l < 512; l += 4) {
        float x = xe[(size_t)b * 8192 + l * 16 + c];
        s += x; sq += x * x;
    }
    s += __shfl_xor(s, 16);  s += __shfl_xor(s, 32);
    sq += __shfl_xor(sq, 16); sq += __shfl_xor(sq, 32);
    if (part == 0) {
        float m = s * (1.0f / 512.0f);
        mean[b * 16 + c] = m;
        stdv[b * 16 + c] = sqrtf(sq * (1.0f / 512.0f) - m * m + 1e-5f);
    }
}

// ---------- projector: circ conv over C axis + 3-layer MLP ----------
__global__ __launch_bounds__(128)
void proj_kernel(const float* __restrict__ xe, const float* __restrict__ stats,
                 const float* __restrict__ cw, const float* __restrict__ w0,
                 const float* __restrict__ b0, const float* __restrict__ w1,
                 const float* __restrict__ b1, const float* __restrict__ w2,
                 float* __restrict__ outp, int outn, int do_exp) {
    __shared__ float zl[32], h0l[128], h1l[128], red[2];
    int b = blockIdx.x, tid = threadIdx.x;
    {   // y[c] = sum_{l,t} x[b,l,(c-1+t)%16] * cw[l,t]
        int c = tid >> 3, part = tid & 7;
        float acc = 0.f;
        for (int l = part; l < 512; l += 8) {
            const float* xr = xe + (size_t)b * 8192 + l * 16;
            float w0v = cw[l * 3 + 0], w1v = cw[l * 3 + 1], w2v = cw[l * 3 + 2];
            acc += xr[(c + 15) & 15] * w0v + xr[c] * w1v + xr[(c + 1) & 15] * w2v;
        }
        acc += __shfl_xor(acc, 1); acc += __shfl_xor(acc, 2); acc += __shfl_xor(acc, 4);
        if (part == 0) zl[c] = acc;
        if (tid < 16) zl[16 + tid] = stats[b * 16 + tid];
    }
    __syncthreads();
    {
        float acc = b0[tid];
        #pragma unroll
        for (int i = 0; i < 32; ++i) acc += zl[i] * w0[tid * 32 + i];
        h0l[tid] = fmaxf(acc, 0.0f);
    }
    __syncthreads();
    {
        float acc = b1[tid];
        for (int i = 0; i < 128; ++i) acc += h0l[i] * w1[tid * 128 + i];
        h1l[tid] = fmaxf(acc, 0.0f);
    }
    __syncthreads();
    if (outn == 1) {
        float p = h1l[tid] * w2[tid];
        p += __shfl_xor(p, 1);  p += __shfl_xor(p, 2);  p += __shfl_xor(p, 4);
        p += __shfl_xor(p, 8);  p += __shfl_xor(p, 16); p += __shfl_xor(p, 32);
        if ((tid & 63) == 0) red[tid >> 6] = p;
        __syncthreads();
        if (tid == 0) {
            float v = red[0] + red[1];
            outp[b] = do_exp ? expf(v) : v;
        }
    } else {
        for (int l = tid; l < outn; l += 128) {
            float acc = 0.f;
            for (int i = 0; i < 128; ++i) acc += h1l[i] * w2[l * 128 + i];
            outp[(size_t)b * outn + l] = acc;
        }
    }
}

// ---------- token embedding: circular conv over L + positional embedding ----------
__global__ __launch_bounds__(256)
void tokconv_kernel(const float* __restrict__ xe, const float* __restrict__ tw,
                    float* __restrict__ xf, u16* __restrict__ xb) {
    __shared__ float xs[34][16];
    int lt = blockIdx.x, b = blockIdx.y, tid = threadIdx.x;
    int l0 = lt * 32;
    for (int idx = tid; idx < 34 * 16; idx += 256) {
        int r = idx >> 4, c = idx & 15;
        int gl = (l0 - 1 + r + 512) & 511;
        xs[r][c] = xe[(size_t)b * 8192 + gl * 16 + c];
    }
    __syncthreads();
    for (int dd = tid; dd < 512; dd += 256) {
        float twr[48];
        #pragma unroll
        for (int i = 0; i < 48; ++i) twr[i] = tw[dd * 48 + i];
        float freq = expf(-(float)(2 * (dd >> 1)) * 0.0179889460390f); // ln(1e4)/512
        for (int l = 0; l < 32; ++l) {
            float acc = 0.f;
            #pragma unroll
            for (int c = 0; c < 16; ++c) {
                acc += xs[l][c]     * twr[c * 3 + 0];
                acc += xs[l + 1][c] * twr[c * 3 + 1];
                acc += xs[l + 2][c] * twr[c * 3 + 2];
            }
            float ang = (float)(l0 + l) * freq;
            float pe = (dd & 1) ? cosf(ang) : sinf(ang);
            float vv = acc + pe;
            size_t idx = ((size_t)b * 512 + l0 + l) * 512 + dd;
            xf[idx] = vv;
            xb[idx] = f2b(vv);
        }
    }
}

// ---------- bf16 MFMA GEMM: C[M,N] = A[M,K] * B[N,K]^T + bias ----------
// 128x128 tile, BK=32, 4 waves (2x2), global_load_lds staging with source-side
// XOR swizzle (slot ^= (row>>1)&3) so ds_read_b128 fragment loads are ~2-way.
template <int ACT, int OBF>   // ACT: 0 none, 1 gelu.  OBF: 1 -> bf16 out, 0 -> fp32 out
__global__ __launch_bounds__(256)
void gemm_bt(const u16* __restrict__ A, const u16* __restrict__ B,
             const float* __restrict__ bias, void* __restrict__ Cv,
             int M, int N, int K) {
    __shared__ u16 Al[128 * 32];
    __shared__ u16 Bl[128 * 32];
    const int tid = threadIdx.x, wv = tid >> 6, ln = tid & 63;
    const int m0 = blockIdx.y * 128, n0 = blockIdx.x * 128;
    const int wm = (wv >> 1) * 64, wn = (wv & 1) * 64;
    f32x4 acc[4][4] = {};
    const int r0 = wv * 16 + (ln >> 2);
    const int sl = ln & 3;
    for (int kt = 0; kt < K; kt += 32) {
        __syncthreads();
        #pragma unroll
        for (int c = 0; c < 2; ++c) {
            int row = r0 + c * 64;
            int ssl = sl ^ ((row >> 1) & 3);
            int ldsoff = row * 32 + sl * 8;   // elements
            gload_lds16(A + (size_t)(m0 + row) * K + kt + ssl * 8, (char*)Al + ldsoff * 2);
            gload_lds16(B + (size_t)(n0 + row) * K + kt + ssl * 8, (char*)Bl + ldsoff * 2);
        }
        __syncthreads();
        bf16x8 af[4], bfr[4];
        #pragma unroll
        for (int i = 0; i < 4; ++i) {
            int row = wm + i * 16 + (ln & 15);
            int slot = (ln >> 4) ^ ((row >> 1) & 3);
            af[i] = *(const bf16x8*)(Al + row * 32 + slot * 8);
        }
        #pragma unroll
        for (int j = 0; j < 4; ++j) {
            int row = wn + j * 16 + (ln & 15);
            int slot = (ln >> 4) ^ ((row >> 1) & 3);
            bfr[j] = *(const bf16x8*)(Bl + row * 32 + slot * 8);
        }
        #pragma unroll
        for (int i = 0; i < 4; ++i)
            #pragma unroll
            for (int j = 0; j < 4; ++j)
                acc[i][j] = __builtin_amdgcn_mfma_f32_16x16x32_bf16(af[i], bfr[j], acc[i][j], 0, 0, 0);
    }
    #pragma unroll
    for (int j = 0; j < 4; ++j) {
        int col = n0 + wn + j * 16 + (ln & 15);
        float bv = bias[col];
        #pragma unroll
        for (int i = 0; i < 4; ++i) {
            int rbase = m0 + wm + i * 16 + (ln >> 4) * 4;
            #pragma unroll
            for (int r = 0; r < 4; ++r) {
                float v = acc[i][j][r] + bv;
                if (ACT == 1) v = gelu_exact(v);
                size_t idx = (size_t)(rbase + r) * N + col;
                if (OBF) ((u16*)Cv)[idx] = f2b(v);
                else     ((float*)Cv)[idx] = v;
            }
        }
    }
}

// ---------- attention: per (b, h, 128-row tile); 4 waves, 32 q-rows each ----------
// logits = (q.k^T * tau[b] + delta[b,s]) * 0.125 ; softmax over s ; O = P V
__global__ __launch_bounds__(256)
void attn_kernel(const u16* __restrict__ q, const u16* __restrict__ k,
                 const u16* __restrict__ v, const float* __restrict__ tau,
                 const float* __restrict__ delta, u16* __restrict__ o) {
    __shared__ u16 Pl[4 * 32 * 512];   // 128KB, XOR-swizzled per-wave P rows
    __shared__ u16 Kl[128 * 64];       // 16KB, swizzled K tile
    __shared__ u16 Vt[64 * 72];        // 9.2KB, padded V^T tile
    const int tid = threadIdx.x, w = tid >> 6, ln = tid & 63;
    const int lt = blockIdx.x, h = blockIdx.y, b = blockIdx.z;
    const int l0 = lt * 128 + w * 32;
    const size_t bhbase = ((size_t)b * 512) * 512 + h * 64;
    const float ts = tau[b] * 0.125f;
    u16* Pw = Pl + w * (32 * 512);
    const int lo = ln & 15, hi = ln >> 4;

    // Q fragments straight from global (bf16, 16B loads)
    bf16x8 qa[2][2];
    #pragma unroll
    for (int i = 0; i < 2; ++i)
        #pragma unroll
        for (int ks = 0; ks < 2; ++ks)
            qa[i][ks] = *(const bf16x8*)(q + bhbase + (size_t)(l0 + i * 16 + lo) * 512 + ks * 32 + hi * 8);

    float Mx[2][4];
    #pragma unroll
    for (int i = 0; i < 2; ++i)
        #pragma unroll
        for (int r = 0; r < 4; ++r) Mx[i][r] = -1e30f;

    // ---- scores ----
    for (int nt = 0; nt < 4; ++nt) {
        int n0 = nt * 128;
        __syncthreads();
        #pragma unroll
        for (int c = 0; c < 4; ++c) {
            int srow = w * 32 + c * 8 + (ln >> 3);
            int ssl = (ln & 7) ^ (srow & 7);
            gload_lds16(k + bhbase + (size_t)(n0 + srow) * 512 + ssl * 8,
                        (char*)Kl + srow * 128 + (ln & 7) * 16);
        }
        __syncthreads();
        f32x4 sacc[2][8] = {};
        #pragma unroll
        for (int ks = 0; ks < 2; ++ks) {
            #pragma unroll
            for (int jn = 0; jn < 8; ++jn) {
                int srow = jn * 16 + lo;
                int slot = (ks * 4 + hi) ^ (srow & 7);
                bf16x8 kb_ = *(const bf16x8*)(Kl + srow * 64 + slot * 8);
                #pragma unroll
                for (int i = 0; i < 2; ++i)
                    sacc[i][jn] = __builtin_amdgcn_mfma_f32_16x16x32_bf16(qa[i][ks], kb_, sacc[i][jn], 0, 0, 0);
            }
        }
        #pragma unroll
        for (int jn = 0; jn < 8; ++jn) {
            int scol = n0 + jn * 16 + lo;
            float dv = delta[b * 512 + scol] * 0.125f;
            #pragma unroll
            for (int i = 0; i < 2; ++i) {
                #pragma unroll
                for (int r = 0; r < 4; ++r) {
                    float lg = sacc[i][jn][r] * ts + dv;
                    Mx[i][r] = fmaxf(Mx[i][r], lg);
                    int rowl = i * 16 + hi * 4 + r;
                    int byt = rowl * 1024 + ((scol * 2) ^ ((rowl & 7) << 4));
                    Pw[byt >> 1] = f2b(lg);
                }
            }
        }
    }
    __syncthreads();

    // ---- softmax (per-wave rows live in Pw) ----
    float rs[2][4];
    #pragma unroll
    for (int i = 0; i < 2; ++i) {
        #pragma unroll
        for (int r = 0; r < 4; ++r) {
            float m = Mx[i][r];
            m = fmaxf(m, __shfl_xor(m, 1)); m = fmaxf(m, __shfl_xor(m, 2));
            m = fmaxf(m, __shfl_xor(m, 4)); m = fmaxf(m, __shfl_xor(m, 8));
            int rowl = i * 16 + hi * 4 + r;
            float s = 0.f;
            for (int t = 0; t < 32; ++t) {
                int scol = lo + t * 16;
                int idx = (rowl * 1024 + ((scol * 2) ^ ((rowl & 7) << 4))) >> 1;
                float p = __expf(b2f(Pw[idx]) - m);
                s += p;
                Pw[idx] = f2b(p);
            }
            s += __shfl_xor(s, 1); s += __shfl_xor(s, 2);
            s += __shfl_xor(s, 4); s += __shfl_xor(s, 8);
            rs[i][r] = s;
        }
    }

    // ---- PV ----
    f32x4 oacc[2][4] = {};
    uint4 vreg0, vreg1;
    {
        int s = tid & 63, half = tid >> 6;
        const u16* vp = v + bhbase + (size_t)s * 512 + half * 16;
        vreg0 = *(const uint4*)vp; vreg1 = *(const uint4*)(vp + 8);
    }
    for (int st = 0; st < 8; ++st) {
        __syncthreads();
        {
            int s = tid & 63, half = tid >> 6;
            u16 tmp[16];
            *(uint4*)tmp = vreg0; *(uint4*)(tmp + 8) = vreg1;
            #pragma unroll
            for (int e = 0; e < 16; ++e)
                Vt[(half * 16 + e) * 72 + s] = tmp[e];
        }
        __syncthreads();
        if (st < 7) {
            int s = tid & 63, half = tid >> 6;
            const u16* vp = v + bhbase + (size_t)((st + 1) * 64 + s) * 512 + half * 16;
            vreg0 = *(const uint4*)vp; vreg1 = *(const uint4*)(vp + 8);
        }
        #pragma unroll
        for (int ks = 0; ks < 2; ++ks) {
            bf16x8 pa[2];
            #pragma unroll
            for (int i = 0; i < 2; ++i) {
                int rowl = i * 16 + lo;
                int sbyte = ((st * 64 + ks * 32 + hi * 8) * 2) ^ ((rowl & 7) << 4);
                pa[i] = *(const bf16x8*)((const char*)Pw + rowl * 1024 + sbyte);
            }
            #pragma unroll
            for (int jd = 0; jd < 4; ++jd) {
                bf16x8 vb_ = *(const bf16x8*)(Vt + (jd * 16 + lo) * 72 + ks * 32 + hi * 8);
                #pragma unroll
                for (int i = 0; i < 2; ++i)
                    oacc[i][jd] = __builtin_amdgcn_mfma_f32_16x16x32_bf16(pa[i], vb_, oacc[i][jd], 0, 0, 0);
            }
        }
    }
    #pragma unroll
    for (int i = 0; i < 2; ++i) {
        #pragma unroll
        for (int jd = 0; jd < 4; ++jd) {
            #pragma unroll
            for (int r = 0; r < 4; ++r) {
                int row = l0 + i * 16 + hi * 4 + r;
                int dh = jd * 16 + lo;
                o[bhbase + (size_t)row * 512 + dh] = f2b(oacc[i][jd][r] / rs[i][r]);
            }
        }
    }
}

// ---------- layernorm with residual: x = LN(x + res); writes fp32 + bf16 ----------
__global__ __launch_bounds__(256)
void ln_kernel(const float* __restrict__ xin, const float* __restrict__ res,
               const float* __restrict__ g, const float* __restrict__ bta,
               float* __restrict__ xout, u16* __restrict__ xbf) {
    const int row = blockIdx.x * 4 + (threadIdx.x >> 6);
    const int ln = threadIdx.x & 63;
    const float* xr = xin + (size_t)row * 512;
    const float* rr = res + (size_t)row * 512;
    float4 a = *(const float4*)(xr + ln * 4);
    float4 c = *(const float4*)(xr + 256 + ln * 4);
    float4 ra = *(const float4*)(rr + ln * 4);
    float4 rc = *(const float4*)(rr + 256 + ln * 4);
    a.x += ra.x; a.y += ra.y; a.z += ra.z; a.w += ra.w;
    c.x += rc.x; c.y += rc.y; c.z += rc.z; c.w += rc.w;
    float s = a.x + a.y + a.z + a.w + c.x + c.y + c.z + c.w;
    float sq = a.x*a.x + a.y*a.y + a.z*a.z + a.w*a.w + c.x*c.x + c.y*c.y + c.z*c.z + c.w*c.w;
    #pragma unroll
    for (int m = 1; m < 64; m <<= 1) { s += __shfl_xor(s, m); sq += __shfl_xor(sq, m); }
    float mean = s * 0.001953125f;
    float var = sq * 0.001953125f - mean * mean;
    float rstd = rsqrtf(var + 1e-5f);
    float4 g0 = *(const float4*)(g + ln * 4);
    float4 g1 = *(const float4*)(g + 256 + ln * 4);
    float4 b0 = *(const float4*)(bta + ln * 4);
    float4 b1 = *(const float4*)(bta + 256 + ln * 4);
    float4 o0, o1;
    o0.x = (a.x - mean) * rstd * g0.x + b0.x;
    o0.y = (a.y - mean) * rstd * g0.y + b0.y;
    o0.z = (a.z - mean) * rstd * g0.z + b0.z;
    o0.w = (a.w - mean) * rstd * g0.w + b0.w;
    o1.x = (c.x - mean) * rstd * g1.x + b1.x;
    o1.y = (c.y - mean) * rstd * g1.y + b1.y;
    o1.z = (c.z - mean) * rstd * g1.z + b1.z;
    o1.w = (c.w - mean) * rstd * g1.w + b1.w;
    *(float4*)(xout + (size_t)row * 512 + ln * 4) = o0;
    *(float4*)(xout + (size_t)row * 512 + 256 + ln * 4) = o1;
    u16 t0[4] = {f2b(o0.x), f2b(o0.y), f2b(o0.z), f2b(o0.w)};
    u16 t1[4] = {f2b(o1.x), f2b(o1.y), f2b(o1.z), f2b(o1.w)};
    *(uint2*)(xbf + (size_t)row * 512 + ln * 4) = *(const uint2*)t0;
    *(uint2*)(xbf + (size_t)row * 512 + 256 + ln * 4) = *(const uint2*)t1;
}

// ---------- final LN -> gelu -> * mark -> bf16 ----------
__global__ __launch_bounds__(256)
void lngelu_kernel(const float* __restrict__ xin, const float* __restrict__ g,
                   const float* __restrict__ bta, const float* __restrict__ mark,
                   u16* __restrict__ outb) {
    const int row = blockIdx.x * 4 + (threadIdx.x >> 6);
    const int ln = threadIdx.x & 63;
    const float* xr = xin + (size_t)row * 512;
    float4 a = *(const float4*)(xr + ln * 4);
    float4 c = *(const float4*)(xr + 256 + ln * 4);
    float s = a.x + a.y + a.z + a.w + c.x + c.y + c.z + c.w;
    float sq = a.x*a.x + a.y*a.y + a.z*a.z + a.w*a.w + c.x*c.x + c.y*c.y + c.z*c.z + c.w*c.w;
    #pragma unroll
    for (int m = 1; m < 64; m <<= 1) { s += __shfl_xor(s, m); sq += __shfl_xor(sq, m); }
    float mean = s * 0.001953125f;
    float var = sq * 0.001953125f - mean * mean;
    float rstd = rsqrtf(var + 1e-5f);
    float mk = mark[row];
    float4 g0 = *(const float4*)(g + ln * 4);
    float4 g1 = *(const float4*)(g + 256 + ln * 4);
    float4 b0 = *(const float4*)(bta + ln * 4);
    float4 b1 = *(const float4*)(bta + 256 + ln * 4);
    float v0 = gelu_exact((a.x - mean) * rstd * g0.x + b0.x) * mk;
    float v1 = gelu_exact((a.y - mean) * rstd * g0.y + b0.y) * mk;
    float v2 = gelu_exact((a.z - mean) * rstd * g0.z + b0.z) * mk;
    float v3 = gelu_exact((a.w - mean) * rstd * g0.w + b0.w) * mk;
    float v4 = gelu_exact((c.x - mean) * rstd * g1.x + b1.x) * mk;
    float v5 = gelu_exact((c.y - mean) * rstd * g1.y + b1.y) * mk;
    float v6 = gelu_exact((c.z - mean) * rstd * g1.z + b1.z) * mk;
    float v7 = gelu_exact((c.w - mean) * rstd * g1.w + b1.w) * mk;
    u16 t0[4] = {f2b(v0), f2b(v1), f2b(v2), f2b(v3)};
    u16 t1[4] = {f2b(v4), f2b(v5), f2b(v6), f2b(v7)};
    *(uint2*)(outb + (size_t)row * 512 + ln * 4) = *(const uint2*)t0;
    *(uint2*)(outb + (size_t)row * 512 + 256 + ln * 4) = *(const uint2*)t1;
}

// ---------- final projection: out[32,10] = gb[32,262144] @ pw[10,262144]^T + pb ----------
__global__ __launch_bounds__(256)
void fproj_kernel(const u16* __restrict__ gb, const u16* __restrict__ pw,
                  const float* __restrict__ pb, float* __restrict__ out) {
    __shared__ float red[32][4];
    int n = blockIdx.x, ks = blockIdx.y, tid = threadIdx.x;
    float acc[32];
    #pragma unroll
    for (int m = 0; m < 32; ++m) acc[m] = 0.f;
    for (int j = 0; j < 8; ++j) {
        size_t k0 = (size_t)ks * 16384 + j * 2048 + tid * 8;
        bf16x8 w8 = *(const bf16x8*)(pw + (size_t)n * 262144 + k0);
        float wf[8];
        #pragma unroll
        for (int e = 0; e < 8; ++e) wf[e] = b2f((u16)w8[e]);
        #pragma unroll
        for (int m = 0; m < 32; ++m) {
            bf16x8 g8 = *(const bf16x8*)(gb + (size_t)m * 262144 + k0);
            float a = acc[m];
            #pragma unroll
            for (int e = 0; e < 8; ++e) a += b2f((u16)g8[e]) * wf[e];
            acc[m] = a;
        }
    }
    int w = tid >> 6;
    #pragma unroll
    for (int m = 0; m < 32; ++m) {
        float s = acc[m];
        s += __shfl_xor(s, 1);  s += __shfl_xor(s, 2);  s += __shfl_xor(s, 4);
        s += __shfl_xor(s, 8);  s += __shfl_xor(s, 16); s += __shfl_xor(s, 32);
        if ((tid & 63) == 0) red[m][w] = s;
    }
    __syncthreads();
    if (tid < 32) {
        int m = tid;
        float s = red[m][0] + red[m][1] + red[m][2] + red[m][3];
        if (ks == 0) s += pb[n];
        atomicAdd(&out[m * 10 + n], s);
    }
}

// =================== host ===================
extern "C" void kernel_launch(void* const* d_in, const int* in_sizes, int n_in,
                              void* d_out, int out_size, void* d_ws, size_t ws_size,
                              hipStream_t stream) {
    const float* x_enc  = (const float*)d_in[0];
    const float* x_mark = (const float*)d_in[1];
    const float* tok_w  = (const float*)d_in[2];
    const float* Wq = (const float*)d_in[3];   const float* bq = (const float*)d_in[4];
    const float* Wk = (const float*)d_in[5];   const float* bk = (const float*)d_in[6];
    const float* Wv = (const float*)d_in[7];   const float* bv = (const float*)d_in[8];
    const float* Wo = (const float*)d_in[9];   const float* bo = (const float*)d_in[10];
    const float* W1 = (const float*)d_in[11];  const float* b1 = (const float*)d_in[12];
    const float* W2 = (const float*)d_in[13];  const float* b2 = (const float*)d_in[14];
    const float* ln1_g = (const float*)d_in[15]; const float* ln1_b = (const float*)d_in[16];
    const float* ln2_g = (const float*)d_in[17]; const float* ln2_b = (const float*)d_in[18];
    const float* norm_g = (const float*)d_in[19]; const float* norm_b = (const float*)d_in[20];
    const float* proj_w = (const float*)d_in[21]; const float* proj_b = (const float*)d_in[22];
    const float* tau_cw = (const float*)d_in[23];
    const float* tau_w0 = (const float*)d_in[24]; const float* tau_b0 = (const float*)d_in[25];
    const float* tau_w1 = (const float*)d_in[26]; const float* tau_b1 = (const float*)d_in[27];
    const float* tau_w2 = (const float*)d_in[28];
    const float* del_cw = (const float*)d_in[29];
    const float* del_w0 = (const float*)d_in[30]; const float* del_b0 = (const float*)d_in[31];
    const float* del_w1 = (const float*)d_in[32]; const float* del_b1 = (const float*)d_in[33];
    const float* del_w2 = (const float*)d_in[34];
    float* out = (float*)d_out;

    char* ws = (char*)d_ws;
    size_t off = 0;
    auto alloc = [&](size_t bytes) -> void* {
        void* p = ws + off;
        off += (bytes + 255) & ~(size_t)255;
        return p;
    };
    u16* wqb = (u16*)alloc(786432 * 2);
    u16* wkb = (u16*)alloc(786432 * 2);
    u16* wvb = (u16*)alloc(786432 * 2);
    u16* wob = (u16*)alloc(786432 * 2);
    u16* w1b = (u16*)alloc(3145728 * 2);
    u16* w2b = (u16*)alloc(3145728 * 2);
    u16* pwb = (u16*)alloc(2621440 * 2);
    float* meanb = (float*)alloc(512 * 4);
    float* stdb  = (float*)alloc(512 * 4);
    float* taub  = (float*)alloc(32 * 4);
    float* delb  = (float*)alloc(16384 * 4);
    float* xf = (float*)alloc((size_t)8388608 * 4);
    u16*  xb  = (u16*)alloc((size_t)8388608 * 2);
    float* sf = (float*)alloc((size_t)8388608 * 4);
    u16* qb = (u16*)alloc((size_t)8388608 * 2);
    u16* kb2 = (u16*)alloc((size_t)8388608 * 2);
    u16* vb2 = (u16*)alloc((size_t)8388608 * 2);
    u16* ob = (u16*)alloc((size_t)8388608 * 2);
    u16* hb = qb;       // FFN hidden (16384x2048 bf16) overlays q/k/v/o (dead then)
    u16* gbuf = qb;     // final gelu buffer overlays too

    auto cvt = [&](const float* src, u16* dst, int n) {
        f2b_kernel<<<dim3((n + 2047) / 2048), dim3(256), 0, stream>>>(src, dst, n);
    };
    cvt(Wq, wqb, 786432);  cvt(Wk, wkb, 786432);
    cvt(Wv, wvb, 786432);  cvt(Wo, wob, 786432);
    cvt(W1, w1b, 3145728); cvt(W2, w2b, 3145728);
    cvt(proj_w, pwb, 2621440);

    stats_kernel<<<dim3(32), dim3(64), 0, stream>>>(x_enc, meanb, stdb);
    proj_kernel<<<dim3(32), dim3(128), 0, stream>>>(x_enc, stdb, tau_cw, tau_w0, tau_b0,
                                                    tau_w1, tau_b1, tau_w2, taub, 1, 1);
    proj_kernel<<<dim3(32), dim3(128), 0, stream>>>(x_enc, meanb, del_cw, del_w0, del_b0,
                                                    del_w1, del_b1, del_w2, delb, 512, 0);
    tokconv_kernel<<<dim3(16, 32), dim3(256), 0, stream>>>(x_enc, tok_w, xf, xb);

    for (int i = 0; i < 3; ++i) {
        const u16* wq_i = wqb + (size_t)i * 262144;
        const u16* wk_i = wkb + (size_t)i * 262144;
        const u16* wv_i = wvb + (size_t)i * 262144;
        const u16* wo_i = wob + (size_t)i * 262144;
        const u16* w1_i = w1b + (size_t)i * 1048576;
        const u16* w2_i = w2b + (size_t)i * 1048576;
        gemm_bt<0, 1><<<dim3(4, 128), dim3(256), 0, stream>>>(xb, wq_i, bq + i * 512, qb, 16384, 512, 512);
        gemm_bt<0, 1><<<dim3(4, 128), dim3(256), 0, stream>>>(xb, wk_i, bk + i * 512, kb2, 16384, 512, 512);
        gemm_bt<0, 1><<<dim3(4, 128), dim3(256), 0, stream>>>(xb, wv_i, bv + i * 512, vb2, 16384, 512, 512);
        attn_kernel<<<dim3(4, 8, 32), dim3(256), 0, stream>>>(qb, kb2, vb2, taub, delb, ob);
        gemm_bt<0, 0><<<dim3(4, 128), dim3(256), 0, stream>>>(ob, wo_i, bo + i * 512, sf, 16384, 512, 512);
        ln_kernel<<<dim3(4096), dim3(256), 0, stream>>>(xf, sf, ln1_g + i * 512, ln1_b + i * 512, xf, xb);
        gemm_bt<1, 1><<<dim3(16, 128), dim3(256), 0, stream>>>(xb, w1_i, b1 + i * 2048, hb, 16384, 2048, 512);
        gemm_bt<0, 0><<<dim3(4, 128), dim3(256), 0, stream>>>(hb, w2_i, b2 + i * 512, sf, 16384, 512, 2048);
        ln_kernel<<<dim3(4096), dim3(256), 0, stream>>>(xf, sf, ln2_g + i * 512, ln2_b + i * 512, xf, xb);
    }

    lngelu_kernel<<<dim3(4096), dim3(256), 0, stream>>>(xf, norm_g, norm_b, x_mark, gbuf);
    hipMemsetAsync(d_out, 0, (size_t)out_size * 4, stream);
    fproj_kernel<<<dim3(10, 16), dim3(256), 0, stream>>>(gbuf, pwb, proj_b, out);
}

// Round 2
// 1029.475 us; speedup vs baseline: 1.2793x; 1.2793x over previous
//
#include <hip/hip_runtime.h>
#include <hip/hip_bf16.h>
#include <cstdint>

#define DEVINL __device__ __forceinline__

typedef unsigned short u16;
typedef short bf16x8 __attribute__((ext_vector_type(8)));
typedef float f32x4 __attribute__((ext_vector_type(4)));

// ---------- small helpers ----------
DEVINL u16 f2b(float f) {
    union { float f; uint32_t u; } x{f};
    uint32_t r = x.u + 0x7fffu + ((x.u >> 16) & 1u);   // RNE
    return (u16)(r >> 16);
}
DEVINL float b2f(u16 h) {
    union { uint32_t u; float f; } x{(uint32_t)h << 16};
    return x.f;
}
DEVINL float gelu_exact(float v) {
    return 0.5f * v * (1.0f + erff(v * 0.70710678118654752f));
}
// global -> LDS async DMA, 16B per lane. LDS dest must be wave-uniform base + lane*16.
DEVINL void gload_lds16(const void* g, void* l) {
    __builtin_amdgcn_global_load_lds(
        (const __attribute__((address_space(1))) void*)(uintptr_t)g,
        (__attribute__((address_space(3))) void*)(uint32_t)(uintptr_t)l,
        16, 0, 0);
}

// ---------- fp32 -> bf16 convert ----------
__global__ void f2b_kernel(const float* __restrict__ in, u16* __restrict__ out, int n) {
    int i = (blockIdx.x * 256 + threadIdx.x) * 8;
    if (i + 8 <= n) {
        float4 a = *(const float4*)(in + i);
        float4 b = *(const float4*)(in + i + 4);
        u16 t[8] = {f2b(a.x), f2b(a.y), f2b(a.z), f2b(a.w),
                    f2b(b.x), f2b(b.y), f2b(b.z), f2b(b.w)};
        *(uint4*)(out + i) = *(const uint4*)t;
    }
}

// ---------- pack qkv biases into [3][1536] ----------
__global__ void packb_kernel(const float* __restrict__ bq, const float* __restrict__ bk,
                             const float* __restrict__ bv, float* __restrict__ out) {
    int idx = blockIdx.x * 256 + threadIdx.x;
    if (idx >= 3 * 1536) return;
    int i = idx / 1536, j = idx - i * 1536;
    float v = (j < 512) ? bq[i * 512 + j]
            : (j < 1024) ? bk[i * 512 + j - 512]
                         : bv[i * 512 + j - 1024];
    out[idx] = v;
}

// ---------- positional-embedding table [512][512] ----------
__global__ void pe_kernel(float* __restrict__ pet) {
    int l = blockIdx.x, d2 = threadIdx.x;   // 256 threads: d2 = d>>1
    float freq = expf(-(float)(2 * d2) * 0.0179889460390f); // ln(1e4)/512
    float ang = (float)l * freq;
    pet[l * 512 + 2 * d2]     = sinf(ang);
    pet[l * 512 + 2 * d2 + 1] = cosf(ang);
}

// ---------- per-(b,c) mean/std over L ----------
__global__ void stats_kernel(const float* __restrict__ xe, float* __restrict__ mean,
                             float* __restrict__ stdv) {
    int b = blockIdx.x, ln = threadIdx.x;          // 64 threads
    int c = ln & 15, part = ln >> 4;
    float s = 0.f, sq = 0.f;
    for (int l = part; l < 512; l += 4) {
        float x = xe[(size_t)b * 8192 + l * 16 + c];
        s += x; sq += x * x;
    }
    s += __shfl_xor(s, 16);  s += __shfl_xor(s, 32);
    sq += __shfl_xor(sq, 16); sq += __shfl_xor(sq, 32);
    if (part == 0) {
        float m = s * (1.0f / 512.0f);
        mean[b * 16 + c] = m;
        stdv[b * 16 + c] = sqrtf(sq * (1.0f / 512.0f) - m * m + 1e-5f);
    }
}

// ---------- projector: circ conv over C axis + 3-layer MLP ----------
__global__ __launch_bounds__(128)
void proj_kernel(const float* __restrict__ xe, const float* __restrict__ stats,
                 const float* __restrict__ cw, const float* __restrict__ w0,
                 const float* __restrict__ b0, const float* __restrict__ w1,
                 const float* __restrict__ b1, const float* __restrict__ w2,
                 float* __restrict__ outp, int outn, int do_exp) {
    __shared__ float zl[32], h0l[128], h1l[128], red[2];
    int b = blockIdx.x, tid = threadIdx.x;
    {   // y[c] = sum_{l,t} x[b,l,(c-1+t)%16] * cw[l,t]
        int c = tid >> 3, part = tid & 7;
        float acc = 0.f;
        for (int l = part; l < 512; l += 8) {
            const float* xr = xe + (size_t)b * 8192 + l * 16;
            float w0v = cw[l * 3 + 0], w1v = cw[l * 3 + 1], w2v = cw[l * 3 + 2];
            acc += xr[(c + 15) & 15] * w0v + xr[c] * w1v + xr[(c + 1) & 15] * w2v;
        }
        acc += __shfl_xor(acc, 1); acc += __shfl_xor(acc, 2); acc += __shfl_xor(acc, 4);
        if (part == 0) zl[c] = acc;
        if (tid < 16) zl[16 + tid] = stats[b * 16 + tid];
    }
    __syncthreads();
    {
        float acc = b0[tid];
        #pragma unroll
        for (int i = 0; i < 32; ++i) acc += zl[i] * w0[tid * 32 + i];
        h0l[tid] = fmaxf(acc, 0.0f);
    }
    __syncthreads();
    {
        float acc = b1[tid];
        for (int i = 0; i < 128; ++i) acc += h0l[i] * w1[tid * 128 + i];
        h1l[tid] = fmaxf(acc, 0.0f);
    }
    __syncthreads();
    if (outn == 1) {
        float p = h1l[tid] * w2[tid];
        p += __shfl_xor(p, 1);  p += __shfl_xor(p, 2);  p += __shfl_xor(p, 4);
        p += __shfl_xor(p, 8);  p += __shfl_xor(p, 16); p += __shfl_xor(p, 32);
        if ((tid & 63) == 0) red[tid >> 6] = p;
        __syncthreads();
        if (tid == 0) {
            float v = red[0] + red[1];
            outp[b] = do_exp ? expf(v) : v;
        }
    } else {
        for (int l = tid; l < outn; l += 128) {
            float acc = 0.f;
            for (int i = 0; i < 128; ++i) acc += h1l[i] * w2[l * 128 + i];
            outp[(size_t)b * outn + l] = acc;
        }
    }
}

// ---------- token embedding: circular conv over L + positional embedding ----------
__global__ __launch_bounds__(256)
void tokconv_kernel(const float* __restrict__ xe, const float* __restrict__ tw,
                    const float* __restrict__ pet,
                    float* __restrict__ xf, u16* __restrict__ xb) {
    __shared__ float xs[34][16];
    int lt = blockIdx.x, b = blockIdx.y, tid = threadIdx.x;
    int l0 = lt * 32;
    for (int idx = tid; idx < 34 * 16; idx += 256) {
        int r = idx >> 4, c = idx & 15;
        int gl = (l0 - 1 + r + 512) & 511;
        xs[r][c] = xe[(size_t)b * 8192 + gl * 16 + c];
    }
    __syncthreads();
    for (int dd = tid; dd < 512; dd += 256) {
        float twr[48];
        #pragma unroll
        for (int i = 0; i < 48; ++i) twr[i] = tw[dd * 48 + i];
        for (int l = 0; l < 32; ++l) {
            float acc = 0.f;
            #pragma unroll
            for (int c = 0; c < 16; ++c) {
                acc += xs[l][c]     * twr[c * 3 + 0];
                acc += xs[l + 1][c] * twr[c * 3 + 1];
                acc += xs[l + 2][c] * twr[c * 3 + 2];
            }
            float vv = acc + pet[(size_t)(l0 + l) * 512 + dd];
            size_t idx = ((size_t)b * 512 + l0 + l) * 512 + dd;
            xf[idx] = vv;
            xb[idx] = f2b(vv);
        }
    }
}

// ---------- bf16 MFMA GEMM: C[M,N] = A[M,K] * B[N,K]^T + bias ----------
template <int ACT, int OBF>   // ACT: 0 none, 1 gelu.  OBF: 1 -> bf16 out, 0 -> fp32 out
__global__ __launch_bounds__(256)
void gemm_bt(const u16* __restrict__ A, const u16* __restrict__ B,
             const float* __restrict__ bias, void* __restrict__ Cv,
             int M, int N, int K) {
    __shared__ u16 Al[128 * 32];
    __shared__ u16 Bl[128 * 32];
    const int tid = threadIdx.x, wv = tid >> 6, ln = tid & 63;
    const int m0 = blockIdx.y * 128, n0 = blockIdx.x * 128;
    const int wm = (wv >> 1) * 64, wn = (wv & 1) * 64;
    f32x4 acc[4][4] = {};
    const int r0 = wv * 16 + (ln >> 2);
    const int sl = ln & 3;
    for (int kt = 0; kt < K; kt += 32) {
        __syncthreads();
        #pragma unroll
        for (int c = 0; c < 2; ++c) {
            int row = r0 + c * 64;
            int ssl = sl ^ ((row >> 1) & 3);
            int ldsoff = row * 32 + sl * 8;   // elements
            gload_lds16(A + (size_t)(m0 + row) * K + kt + ssl * 8, (char*)Al + ldsoff * 2);
            gload_lds16(B + (size_t)(n0 + row) * K + kt + ssl * 8, (char*)Bl + ldsoff * 2);
        }
        __syncthreads();
        bf16x8 af[4], bfr[4];
        #pragma unroll
        for (int i = 0; i < 4; ++i) {
            int row = wm + i * 16 + (ln & 15);
            int slot = (ln >> 4) ^ ((row >> 1) & 3);
            af[i] = *(const bf16x8*)(Al + row * 32 + slot * 8);
        }
        #pragma unroll
        for (int j = 0; j < 4; ++j) {
            int row = wn + j * 16 + (ln & 15);
            int slot = (ln >> 4) ^ ((row >> 1) & 3);
            bfr[j] = *(const bf16x8*)(Bl + row * 32 + slot * 8);
        }
        #pragma unroll
        for (int i = 0; i < 4; ++i)
            #pragma unroll
            for (int j = 0; j < 4; ++j)
                acc[i][j] = __builtin_amdgcn_mfma_f32_16x16x32_bf16(af[i], bfr[j], acc[i][j], 0, 0, 0);
    }
    #pragma unroll
    for (int j = 0; j < 4; ++j) {
        int col = n0 + wn + j * 16 + (ln & 15);
        float bv = bias[col];
        #pragma unroll
        for (int i = 0; i < 4; ++i) {
            int rbase = m0 + wm + i * 16 + (ln >> 4) * 4;
            #pragma unroll
            for (int r = 0; r < 4; ++r) {
                float v = acc[i][j][r] + bv;
                if (ACT == 1) v = gelu_exact(v);
                size_t idx = (size_t)(rbase + r) * N + col;
                if (OBF) ((u16*)Cv)[idx] = f2b(v);
                else     ((float*)Cv)[idx] = v;
            }
        }
    }
}

// ---------- attention v2: flash-style, swapped-operand MFMA ----------
// block (qh, h, b): 512 threads = 8 waves; wave w owns q rows q0..q0+31.
// KVBLK = 64, 8 tiles. logits = qk*tau*0.125 + delta[s]*0.125; online softmax.
// Score: mfma(K,Q) -> D[s][q] (col=q=lane&15, rows=4 consec s) -> 8B P stores.
// PV:    mfma(V^T,P) -> D[d][q] (col=q, rows=4 consec d) -> 8B O stores.
__global__ __launch_bounds__(512)
void attn2_kernel(const u16* __restrict__ qkv, const float* __restrict__ tau,
                  const float* __restrict__ delta, u16* __restrict__ o) {
    __shared__ u16 KL[64 * 64];        // [s][dh], slot16 phys = j ^ (s&7), src pre-swizzled
    __shared__ u16 VT[64 * 72];        // [d][s_l], stride 144B, col-slot16 phys = c ^ ((d>>3)&7)
    __shared__ u16 PL[8][32 * 64];     // per-wave P [q][s], slot16 phys = ls ^ (q&7)
    const int tid = threadIdx.x, w = tid >> 6, ln = tid & 63;
    const int lo = ln & 15, hi = ln >> 4;
    const int qh = blockIdx.x, h = blockIdx.y, b = blockIdx.z;
    const size_t qrow0 = (size_t)b * 512;
    const u16* qp = qkv;
    const u16* kp = qkv + 512;
    const u16* vp = qkv + 1024;
    const int hofs = h * 64;
    const float ts = tau[b] * 0.125f;
    u16* Pw = (u16*)PL[w];
    const int q0 = qh * 256 + w * 32;

    // Q fragments (B-operand): lane holds Q[q=i*16+lo][dh=ks*32+hi*8 ..+8]
    bf16x8 qa[2][2];
    #pragma unroll
    for (int i = 0; i < 2; ++i)
        #pragma unroll
        for (int ks = 0; ks < 2; ++ks)
            qa[i][ks] = *(const bf16x8*)(qp + (qrow0 + q0 + i * 16 + lo) * 1536 + hofs + ks * 32 + hi * 8);

    float m_run[2] = {-1e30f, -1e30f};
    float l_run[2] = {0.f, 0.f};
    f32x4 oacc[2][4] = {};

    // V prefetch: thread covers (row s_l = tid>>3, d0 = (tid&7)*8)
    const int vsl = tid & 7, vsr = tid >> 3;
    uint4 vreg = *(const uint4*)(vp + (qrow0 + vsr) * 1536 + hofs + vsl * 8);

    for (int nt = 0; nt < 8; ++nt) {
        __syncthreads();
        // stage K tile (pre-swizzled source so reads are conflict-light)
        {
            int s = tid >> 3, j = tid & 7;
            int jl = j ^ (s & 7);
            gload_lds16(kp + (qrow0 + nt * 64 + s) * 1536 + hofs + jl * 8,
                        (char*)KL + tid * 16);
        }
        // transpose V tile into VT (col-slot swizzled by (d>>3)&7 = vsl)
        {
            u16 tmp[8]; *(uint4*)tmp = vreg;
            #pragma unroll
            for (int e = 0; e < 8; ++e) {
                int d = vsl * 8 + e;
                int byt = d * 144 + (((vsr >> 3) ^ vsl) << 4) + (vsr & 7) * 2;
                *(u16*)((char*)VT + byt) = tmp[e];
            }
        }
        if (nt < 7)
            vreg = *(const uint4*)(vp + (qrow0 + (nt + 1) * 64 + vsr) * 1536 + hofs + vsl * 8);
        __syncthreads();

        // ---- QK^T (swapped): sacc[i][jn]: q=q0+i*16+lo, s=nt*64+jn*16+hi*4+r
        f32x4 sacc[2][4] = {};
        #pragma unroll
        for (int ks = 0; ks < 2; ++ks) {
            #pragma unroll
            for (int jn = 0; jn < 4; ++jn) {
                int s = jn * 16 + lo;
                int phys = (ks * 4 + hi) ^ (s & 7);
                bf16x8 kb = *(const bf16x8*)((const char*)KL + s * 128 + phys * 16);
                #pragma unroll
                for (int i = 0; i < 2; ++i)
                    sacc[i][jn] = __builtin_amdgcn_mfma_f32_16x16x32_bf16(kb, qa[i][ks], sacc[i][jn], 0, 0, 0);
            }
        }
        // logits in place + tile max
        float tmax[2] = {-1e30f, -1e30f};
        #pragma unroll
        for (int jn = 0; jn < 4; ++jn) {
            float4 dv4 = *(const float4*)(delta + b * 512 + nt * 64 + jn * 16 + hi * 4);
            float dv[4] = {dv4.x, dv4.y, dv4.z, dv4.w};
            #pragma unroll
            for (int i = 0; i < 2; ++i)
                #pragma unroll
                for (int r = 0; r < 4; ++r) {
                    float v = sacc[i][jn][r] * ts + dv[r] * 0.125f;
                    sacc[i][jn][r] = v;
                    tmax[i] = fmaxf(tmax[i], v);
                }
        }
        #pragma unroll
        for (int i = 0; i < 2; ++i) {
            tmax[i] = fmaxf(tmax[i], __shfl_xor(tmax[i], 16));
            tmax[i] = fmaxf(tmax[i], __shfl_xor(tmax[i], 32));
            float mnew = fmaxf(m_run[i], tmax[i]);
            float fac = __expf(m_run[i] - mnew);
            m_run[i] = mnew;
            l_run[i] *= fac;
            #pragma unroll
            for (int jd = 0; jd < 4; ++jd)
                #pragma unroll
                for (int r = 0; r < 4; ++r) oacc[i][jd][r] *= fac;
        }
        // p = exp(lg - m), sum, 8B bf16 stores into Pw
        #pragma unroll
        for (int i = 0; i < 2; ++i) {
            float ls = 0.f;
            #pragma unroll
            for (int jn = 0; jn < 4; ++jn) {
                float p0 = __expf(sacc[i][jn][0] - m_run[i]);
                float p1 = __expf(sacc[i][jn][1] - m_run[i]);
                float p2 = __expf(sacc[i][jn][2] - m_run[i]);
                float p3 = __expf(sacc[i][jn][3] - m_run[i]);
                ls += (p0 + p1) + (p2 + p3);
                uint2 pk;
                pk.x = (uint32_t)f2b(p0) | ((uint32_t)f2b(p1) << 16);
                pk.y = (uint32_t)f2b(p2) | ((uint32_t)f2b(p3) << 16);
                int q = i * 16 + lo;
                int ls16 = jn * 2 + (hi >> 1);
                int byt = q * 128 + (((ls16 ^ (q & 7)) << 4)) + (hi & 1) * 8;
                *(uint2*)((char*)Pw + byt) = pk;
            }
            ls += __shfl_xor(ls, 16);
            ls += __shfl_xor(ls, 32);
            l_run[i] += ls;
        }
        // ---- PV (swapped): D[d][q]; col=q=lane&15, rows = 4 consec d
        #pragma unroll
        for (int ks2 = 0; ks2 < 2; ++ks2) {
            bf16x8 pa[2];
            #pragma unroll
            for (int i = 0; i < 2; ++i) {
                int q = i * 16 + lo;
                int phys = (ks2 * 4 + hi) ^ (q & 7);
                pa[i] = *(const bf16x8*)((const char*)Pw + q * 128 + phys * 16);
            }
            #pragma unroll
            for (int jd = 0; jd < 4; ++jd) {
                int d = jd * 16 + lo;
                int cs = (ks2 * 4 + hi) ^ ((d >> 3) & 7);
                bf16x8 vb = *(const bf16x8*)((const char*)VT + d * 144 + cs * 16);
                #pragma unroll
                for (int i = 0; i < 2; ++i)
                    oacc[i][jd] = __builtin_amdgcn_mfma_f32_16x16x32_bf16(vb, pa[i], oacc[i][jd], 0, 0, 0);
            }
        }
    }
    // epilogue: O[q][d] = oacc / l_run; lane: q = q0+i*16+lo, d = jd*16+hi*4+r
    #pragma unroll
    for (int i = 0; i < 2; ++i) {
        float inv = 1.0f / l_run[i];
        #pragma unroll
        for (int jd = 0; jd < 4; ++jd) {
            u16 t4[4];
            #pragma unroll
            for (int r = 0; r < 4; ++r) t4[r] = f2b(oacc[i][jd][r] * inv);
            size_t row = qrow0 + q0 + i * 16 + lo;
            *(uint2*)(o + row * 512 + hofs + jd * 16 + hi * 4) = *(const uint2*)t4;
        }
    }
}

// ---------- layernorm with residual: x = LN(x + res); writes fp32 + bf16 ----------
__global__ __launch_bounds__(256)
void ln_kernel(const float* __restrict__ xin, const float* __restrict__ res,
               const float* __restrict__ g, const float* __restrict__ bta,
               float* __restrict__ xout, u16* __restrict__ xbf) {
    const int row = blockIdx.x * 4 + (threadIdx.x >> 6);
    const int ln = threadIdx.x & 63;
    const float* xr = xin + (size_t)row * 512;
    const float* rr = res + (size_t)row * 512;
    float4 a = *(const float4*)(xr + ln * 4);
    float4 c = *(const float4*)(xr + 256 + ln * 4);
    float4 ra = *(const float4*)(rr + ln * 4);
    float4 rc = *(const float4*)(rr + 256 + ln * 4);
    a.x += ra.x; a.y += ra.y; a.z += ra.z; a.w += ra.w;
    c.x += rc.x; c.y += rc.y; c.z += rc.z; c.w += rc.w;
    float s = a.x + a.y + a.z + a.w + c.x + c.y + c.z + c.w;
    float sq = a.x*a.x + a.y*a.y + a.z*a.z + a.w*a.w + c.x*c.x + c.y*c.y + c.z*c.z + c.w*c.w;
    #pragma unroll
    for (int m = 1; m < 64; m <<= 1) { s += __shfl_xor(s, m); sq += __shfl_xor(sq, m); }
    float mean = s * 0.001953125f;
    float var = sq * 0.001953125f - mean * mean;
    float rstd = rsqrtf(var + 1e-5f);
    float4 g0 = *(const float4*)(g + ln * 4);
    float4 g1 = *(const float4*)(g + 256 + ln * 4);
    float4 b0 = *(const float4*)(bta + ln * 4);
    float4 b1 = *(const float4*)(bta + 256 + ln * 4);
    float4 o0, o1;
    o0.x = (a.x - mean) * rstd * g0.x + b0.x;
    o0.y = (a.y - mean) * rstd * g0.y + b0.y;
    o0.z = (a.z - mean) * rstd * g0.z + b0.z;
    o0.w = (a.w - mean) * rstd * g0.w + b0.w;
    o1.x = (c.x - mean) * rstd * g1.x + b1.x;
    o1.y = (c.y - mean) * rstd * g1.y + b1.y;
    o1.z = (c.z - mean) * rstd * g1.z + b1.z;
    o1.w = (c.w - mean) * rstd * g1.w + b1.w;
    *(float4*)(xout + (size_t)row * 512 + ln * 4) = o0;
    *(float4*)(xout + (size_t)row * 512 + 256 + ln * 4) = o1;
    u16 t0[4] = {f2b(o0.x), f2b(o0.y), f2b(o0.z), f2b(o0.w)};
    u16 t1[4] = {f2b(o1.x), f2b(o1.y), f2b(o1.z), f2b(o1.w)};
    *(uint2*)(xbf + (size_t)row * 512 + ln * 4) = *(const uint2*)t0;
    *(uint2*)(xbf + (size_t)row * 512 + 256 + ln * 4) = *(const uint2*)t1;
}

// ---------- final LN -> gelu -> * mark -> bf16 ----------
__global__ __launch_bounds__(256)
void lngelu_kernel(const float* __restrict__ xin, const float* __restrict__ g,
                   const float* __restrict__ bta, const float* __restrict__ mark,
                   u16* __restrict__ outb) {
    const int row = blockIdx.x * 4 + (threadIdx.x >> 6);
    const int ln = threadIdx.x & 63;
    const float* xr = xin + (size_t)row * 512;
    float4 a = *(const float4*)(xr + ln * 4);
    float4 c = *(const float4*)(xr + 256 + ln * 4);
    float s = a.x + a.y + a.z + a.w + c.x + c.y + c.z + c.w;
    float sq = a.x*a.x + a.y*a.y + a.z*a.z + a.w*a.w + c.x*c.x + c.y*c.y + c.z*c.z + c.w*c.w;
    #pragma unroll
    for (int m = 1; m < 64; m <<= 1) { s += __shfl_xor(s, m); sq += __shfl_xor(sq, m); }
    float mean = s * 0.001953125f;
    float var = sq * 0.001953125f - mean * mean;
    float rstd = rsqrtf(var + 1e-5f);
    float mk = mark[row];
    float4 g0 = *(const float4*)(g + ln * 4);
    float4 g1 = *(const float4*)(g + 256 + ln * 4);
    float4 b0 = *(const float4*)(bta + ln * 4);
    float4 b1 = *(const float4*)(bta + 256 + ln * 4);
    float v0 = gelu_exact((a.x - mean) * rstd * g0.x + b0.x) * mk;
    float v1 = gelu_exact((a.y - mean) * rstd * g0.y + b0.y) * mk;
    float v2 = gelu_exact((a.z - mean) * rstd * g0.z + b0.z) * mk;
    float v3 = gelu_exact((a.w - mean) * rstd * g0.w + b0.w) * mk;
    float v4 = gelu_exact((c.x - mean) * rstd * g1.x + b1.x) * mk;
    float v5 = gelu_exact((c.y - mean) * rstd * g1.y + b1.y) * mk;
    float v6 = gelu_exact((c.z - mean) * rstd * g1.z + b1.z) * mk;
    float v7 = gelu_exact((c.w - mean) * rstd * g1.w + b1.w) * mk;
    u16 t0[4] = {f2b(v0), f2b(v1), f2b(v2), f2b(v3)};
    u16 t1[4] = {f2b(v4), f2b(v5), f2b(v6), f2b(v7)};
    *(uint2*)(outb + (size_t)row * 512 + ln * 4) = *(const uint2*)t0;
    *(uint2*)(outb + (size_t)row * 512 + 256 + ln * 4) = *(const uint2*)t1;
}

// ---------- final projection: out[32,10] = gb[32,262144] @ pw[10,262144]^T + pb ----------
__global__ __launch_bounds__(256)
void fproj_kernel(const u16* __restrict__ gb, const u16* __restrict__ pw,
                  const float* __restrict__ pb, float* __restrict__ out) {
    __shared__ float red[32][4];
    int n = blockIdx.x, ks = blockIdx.y, tid = threadIdx.x;
    float acc[32];
    #pragma unroll
    for (int m = 0; m < 32; ++m) acc[m] = 0.f;
    for (int j = 0; j < 8; ++j) {
        size_t k0 = (size_t)ks * 16384 + j * 2048 + tid * 8;
        bf16x8 w8 = *(const bf16x8*)(pw + (size_t)n * 262144 + k0);
        float wf[8];
        #pragma unroll
        for (int e = 0; e < 8; ++e) wf[e] = b2f((u16)w8[e]);
        #pragma unroll
        for (int m = 0; m < 32; ++m) {
            bf16x8 g8 = *(const bf16x8*)(gb + (size_t)m * 262144 + k0);
            float a = acc[m];
            #pragma unroll
            for (int e = 0; e < 8; ++e) a += b2f((u16)g8[e]) * wf[e];
            acc[m] = a;
        }
    }
    int w = tid >> 6;
    #pragma unroll
    for (int m = 0; m < 32; ++m) {
        float s = acc[m];
        s += __shfl_xor(s, 1);  s += __shfl_xor(s, 2);  s += __shfl_xor(s, 4);
        s += __shfl_xor(s, 8);  s += __shfl_xor(s, 16); s += __shfl_xor(s, 32);
        if ((tid & 63) == 0) red[m][w] = s;
    }
    __syncthreads();
    if (tid < 32) {
        int m = tid;
        float s = red[m][0] + red[m][1] + red[m][2] + red[m][3];
        if (ks == 0) s += pb[n];
        atomicAdd(&out[m * 10 + n], s);
    }
}

// =================== host ===================
extern "C" void kernel_launch(void* const* d_in, const int* in_sizes, int n_in,
                              void* d_out, int out_size, void* d_ws, size_t ws_size,
                              hipStream_t stream) {
    const float* x_enc  = (const float*)d_in[0];
    const float* x_mark = (const float*)d_in[1];
    const float* tok_w  = (const float*)d_in[2];
    const float* Wq = (const float*)d_in[3];   const float* bq = (const float*)d_in[4];
    const float* Wk = (const float*)d_in[5];   const float* bk = (const float*)d_in[6];
    const float* Wv = (const float*)d_in[7];   const float* bv = (const float*)d_in[8];
    const float* Wo = (const float*)d_in[9];   const float* bo = (const float*)d_in[10];
    const float* W1 = (const float*)d_in[11];  const float* b1 = (const float*)d_in[12];
    const float* W2 = (const float*)d_in[13];  const float* b2 = (const float*)d_in[14];
    const float* ln1_g = (const float*)d_in[15]; const float* ln1_b = (const float*)d_in[16];
    const float* ln2_g = (const float*)d_in[17]; const float* ln2_b = (const float*)d_in[18];
    const float* norm_g = (const float*)d_in[19]; const float* norm_b = (const float*)d_in[20];
    const float* proj_w = (const float*)d_in[21]; const float* proj_b = (const float*)d_in[22];
    const float* tau_cw = (const float*)d_in[23];
    const float* tau_w0 = (const float*)d_in[24]; const float* tau_b0 = (const float*)d_in[25];
    const float* tau_w1 = (const float*)d_in[26]; const float* tau_b1 = (const float*)d_in[27];
    const float* tau_w2 = (const float*)d_in[28];
    const float* del_cw = (const float*)d_in[29];
    const float* del_w0 = (const float*)d_in[30]; const float* del_b0 = (const float*)d_in[31];
    const float* del_w1 = (const float*)d_in[32]; const float* del_b1 = (const float*)d_in[33];
    const float* del_w2 = (const float*)d_in[34];
    float* out = (float*)d_out;

    char* ws = (char*)d_ws;
    size_t off = 0;
    auto alloc = [&](size_t bytes) -> void* {
        void* p = ws + off;
        off += (bytes + 255) & ~(size_t)255;
        return p;
    };
    u16* wqkvb = (u16*)alloc((size_t)3 * 786432 * 2);   // per layer [1536][512]
    u16* wob = (u16*)alloc(786432 * 2);
    u16* w1b = (u16*)alloc(3145728 * 2);
    u16* w2b = (u16*)alloc(3145728 * 2);
    u16* pwb = (u16*)alloc(2621440 * 2);
    float* bqkvb = (float*)alloc(3 * 1536 * 4);
    float* petab = (float*)alloc((size_t)262144 * 4);
    float* meanb = (float*)alloc(512 * 4);
    float* stdb  = (float*)alloc(512 * 4);
    float* taub  = (float*)alloc(32 * 4);
    float* delb  = (float*)alloc(16384 * 4);
    float* xf = (float*)alloc((size_t)8388608 * 4);
    u16*  xb  = (u16*)alloc((size_t)8388608 * 2);
    float* sf = (float*)alloc((size_t)8388608 * 4);
    u16* qkvb = (u16*)alloc((size_t)16384 * 1536 * 2);  // 50.3MB
    u16* ob   = (u16*)alloc((size_t)8388608 * 2);       // 16.8MB
    u16* hb   = qkvb;   // FFN hidden (16384x2048 bf16 = 64MB) overlays qkvb+ob (67MB)
    u16* gbuf = qkvb;   // final gelu buffer overlays too

    auto cvt = [&](const float* src, u16* dst, int n) {
        f2b_kernel<<<dim3((n + 2047) / 2048), dim3(256), 0, stream>>>(src, dst, n);
    };
    for (int i = 0; i < 3; ++i) {
        cvt(Wq + (size_t)i * 262144, wqkvb + (size_t)i * 786432 + 0,      262144);
        cvt(Wk + (size_t)i * 262144, wqkvb + (size_t)i * 786432 + 262144, 262144);
        cvt(Wv + (size_t)i * 262144, wqkvb + (size_t)i * 786432 + 524288, 262144);
    }
    cvt(Wo, wob, 786432);
    cvt(W1, w1b, 3145728); cvt(W2, w2b, 3145728);
    cvt(proj_w, pwb, 2621440);
    packb_kernel<<<dim3(18), dim3(256), 0, stream>>>(bq, bk, bv, bqkvb);
    pe_kernel<<<dim3(512), dim3(256), 0, stream>>>(petab);

    stats_kernel<<<dim3(32), dim3(64), 0, stream>>>(x_enc, meanb, stdb);
    proj_kernel<<<dim3(32), dim3(128), 0, stream>>>(x_enc, stdb, tau_cw, tau_w0, tau_b0,
                                                    tau_w1, tau_b1, tau_w2, taub, 1, 1);
    proj_kernel<<<dim3(32), dim3(128), 0, stream>>>(x_enc, meanb, del_cw, del_w0, del_b0,
                                                    del_w1, del_b1, del_w2, delb, 512, 0);
    tokconv_kernel<<<dim3(16, 32), dim3(256), 0, stream>>>(x_enc, tok_w, petab, xf, xb);

    for (int i = 0; i < 3; ++i) {
        const u16* wqkv_i = wqkvb + (size_t)i * 786432;
        const u16* wo_i = wob + (size_t)i * 262144;
        const u16* w1_i = w1b + (size_t)i * 1048576;
        const u16* w2_i = w2b + (size_t)i * 1048576;
        gemm_bt<0, 1><<<dim3(12, 128), dim3(256), 0, stream>>>(xb, wqkv_i, bqkvb + i * 1536, qkvb, 16384, 1536, 512);
        attn2_kernel<<<dim3(2, 8, 32), dim3(512), 0, stream>>>(qkvb, taub, delb, ob);
        gemm_bt<0, 0><<<dim3(4, 128), dim3(256), 0, stream>>>(ob, wo_i, bo + i * 512, sf, 16384, 512, 512);
        ln_kernel<<<dim3(4096), dim3(256), 0, stream>>>(xf, sf, ln1_g + i * 512, ln1_b + i * 512, xf, xb);
        gemm_bt<1, 1><<<dim3(16, 128), dim3(256), 0, stream>>>(xb, w1_i, b1 + i * 2048, hb, 16384, 2048, 512);
        gemm_bt<0, 0><<<dim3(4, 128), dim3(256), 0, stream>>>(hb, w2_i, b2 + i * 512, sf, 16384, 512, 2048);
        ln_kernel<<<dim3(4096), dim3(256), 0, stream>>>(xf, sf, ln2_g + i * 512, ln2_b + i * 512, xf, xb);
    }

    lngelu_kernel<<<dim3(4096), dim3(256), 0, stream>>>(xf, norm_g, norm_b, x_mark, gbuf);
    hipMemsetAsync(d_out, 0, (size_t)out_size * 4, stream);
    fproj_kernel<<<dim3(10, 16), dim3(256), 0, stream>>>(gbuf, pwb, proj_b, out);
}

// Round 3
// 967.215 us; speedup vs baseline: 1.3616x; 1.0644x over previous
//
#include <hip/hip_runtime.h>
#include <hip/hip_bf16.h>
#include <cstdint>

#define DEVINL __device__ __forceinline__

typedef unsigned short u16;
typedef short bf16x8 __attribute__((ext_vector_type(8)));
typedef float f32x4 __attribute__((ext_vector_type(4)));

// ---------- small helpers ----------
DEVINL u16 f2b(float f) {
    union { float f; uint32_t u; } x{f};
    uint32_t r = x.u + 0x7fffu + ((x.u >> 16) & 1u);   // RNE
    return (u16)(r >> 16);
}
DEVINL float b2f(u16 h) {
    union { uint32_t u; float f; } x{(uint32_t)h << 16};
    return x.f;
}
DEVINL float gelu_exact(float v) {
    return 0.5f * v * (1.0f + erff(v * 0.70710678118654752f));
}
// global -> LDS async DMA, 16B per lane. LDS dest must be wave-uniform base + lane*16.
DEVINL void gload_lds16(const void* g, void* l) {
    __builtin_amdgcn_global_load_lds(
        (const __attribute__((address_space(1))) void*)(uintptr_t)g,
        (__attribute__((address_space(3))) void*)(uint32_t)(uintptr_t)l,
        16, 0, 0);
}

// ---------- fp32 -> bf16 convert ----------
__global__ void f2b_kernel(const float* __restrict__ in, u16* __restrict__ out, int n) {
    int i = (blockIdx.x * 256 + threadIdx.x) * 8;
    if (i + 8 <= n) {
        float4 a = *(const float4*)(in + i);
        float4 b = *(const float4*)(in + i + 4);
        u16 t[8] = {f2b(a.x), f2b(a.y), f2b(a.z), f2b(a.w),
                    f2b(b.x), f2b(b.y), f2b(b.z), f2b(b.w)};
        *(uint4*)(out + i) = *(const uint4*)t;
    }
}

// ---------- pack qkv biases into [3][1536] ----------
__global__ void packb_kernel(const float* __restrict__ bq, const float* __restrict__ bk,
                             const float* __restrict__ bv, float* __restrict__ out) {
    int idx = blockIdx.x * 256 + threadIdx.x;
    if (idx >= 3 * 1536) return;
    int i = idx / 1536, j = idx - i * 1536;
    float v = (j < 512) ? bq[i * 512 + j]
            : (j < 1024) ? bk[i * 512 + j - 512]
                         : bv[i * 512 + j - 1024];
    out[idx] = v;
}

// ---------- positional-embedding table [512][512] ----------
__global__ void pe_kernel(float* __restrict__ pet) {
    int l = blockIdx.x, d2 = threadIdx.x;   // 256 threads: d2 = d>>1
    float freq = expf(-(float)(2 * d2) * 0.0179889460390f); // ln(1e4)/512
    float ang = (float)l * freq;
    pet[l * 512 + 2 * d2]     = sinf(ang);
    pet[l * 512 + 2 * d2 + 1] = cosf(ang);
}

// ---------- per-(b,c) mean/std over L ----------
__global__ void stats_kernel(const float* __restrict__ xe, float* __restrict__ mean,
                             float* __restrict__ stdv) {
    int b = blockIdx.x, ln = threadIdx.x;          // 64 threads
    int c = ln & 15, part = ln >> 4;
    float s = 0.f, sq = 0.f;
    for (int l = part; l < 512; l += 4) {
        float x = xe[(size_t)b * 8192 + l * 16 + c];
        s += x; sq += x * x;
    }
    s += __shfl_xor(s, 16);  s += __shfl_xor(s, 32);
    sq += __shfl_xor(sq, 16); sq += __shfl_xor(sq, 32);
    if (part == 0) {
        float m = s * (1.0f / 512.0f);
        mean[b * 16 + c] = m;
        stdv[b * 16 + c] = sqrtf(sq * (1.0f / 512.0f) - m * m + 1e-5f);
    }
}

// ---------- projector: circ conv over C axis + 3-layer MLP ----------
__global__ __launch_bounds__(128)
void proj_kernel(const float* __restrict__ xe, const float* __restrict__ stats,
                 const float* __restrict__ cw, const float* __restrict__ w0,
                 const float* __restrict__ b0, const float* __restrict__ w1,
                 const float* __restrict__ b1, const float* __restrict__ w2,
                 float* __restrict__ outp, int outn, int do_exp) {
    __shared__ float zl[32], h0l[128], h1l[128], red[2];
    int b = blockIdx.x, tid = threadIdx.x;
    {   // y[c] = sum_{l,t} x[b,l,(c-1+t)%16] * cw[l,t]
        int c = tid >> 3, part = tid & 7;
        float acc = 0.f;
        for (int l = part; l < 512; l += 8) {
            const float* xr = xe + (size_t)b * 8192 + l * 16;
            float w0v = cw[l * 3 + 0], w1v = cw[l * 3 + 1], w2v = cw[l * 3 + 2];
            acc += xr[(c + 15) & 15] * w0v + xr[c] * w1v + xr[(c + 1) & 15] * w2v;
        }
        acc += __shfl_xor(acc, 1); acc += __shfl_xor(acc, 2); acc += __shfl_xor(acc, 4);
        if (part == 0) zl[c] = acc;
        if (tid < 16) zl[16 + tid] = stats[b * 16 + tid];
    }
    __syncthreads();
    {
        float acc = b0[tid];
        #pragma unroll
        for (int i = 0; i < 32; ++i) acc += zl[i] * w0[tid * 32 + i];
        h0l[tid] = fmaxf(acc, 0.0f);
    }
    __syncthreads();
    {
        float acc = b1[tid];
        for (int i = 0; i < 128; ++i) acc += h0l[i] * w1[tid * 128 + i];
        h1l[tid] = fmaxf(acc, 0.0f);
    }
    __syncthreads();
    if (outn == 1) {
        float p = h1l[tid] * w2[tid];
        p += __shfl_xor(p, 1);  p += __shfl_xor(p, 2);  p += __shfl_xor(p, 4);
        p += __shfl_xor(p, 8);  p += __shfl_xor(p, 16); p += __shfl_xor(p, 32);
        if ((tid & 63) == 0) red[tid >> 6] = p;
        __syncthreads();
        if (tid == 0) {
            float v = red[0] + red[1];
            outp[b] = do_exp ? expf(v) : v;
        }
    } else {
        for (int l = tid; l < outn; l += 128) {
            float acc = 0.f;
            for (int i = 0; i < 128; ++i) acc += h1l[i] * w2[l * 128 + i];
            outp[(size_t)b * outn + l] = acc;
        }
    }
}

// ---------- token embedding: circular conv over L + positional embedding ----------
__global__ __launch_bounds__(256)
void tokconv_kernel(const float* __restrict__ xe, const float* __restrict__ tw,
                    const float* __restrict__ pet,
                    float* __restrict__ xf, u16* __restrict__ xb) {
    __shared__ float xs[34][16];
    int lt = blockIdx.x, b = blockIdx.y, tid = threadIdx.x;
    int l0 = lt * 32;
    for (int idx = tid; idx < 34 * 16; idx += 256) {
        int r = idx >> 4, c = idx & 15;
        int gl = (l0 - 1 + r + 512) & 511;
        xs[r][c] = xe[(size_t)b * 8192 + gl * 16 + c];
    }
    __syncthreads();
    for (int dd = tid; dd < 512; dd += 256) {
        float twr[48];
        #pragma unroll
        for (int i = 0; i < 48; ++i) twr[i] = tw[dd * 48 + i];
        for (int l = 0; l < 32; ++l) {
            float acc = 0.f;
            #pragma unroll
            for (int c = 0; c < 16; ++c) {
                acc += xs[l][c]     * twr[c * 3 + 0];
                acc += xs[l + 1][c] * twr[c * 3 + 1];
                acc += xs[l + 2][c] * twr[c * 3 + 2];
            }
            float vv = acc + pet[(size_t)(l0 + l) * 512 + dd];
            size_t idx = ((size_t)b * 512 + l0 + l) * 512 + dd;
            xf[idx] = vv;
            xb[idx] = f2b(vv);
        }
    }
}

// ---------- bf16 MFMA GEMM v2: C[M,N] = A[M,K] * B[N,K]^T + bias ----------
// 128x128 tile, BK=32, 4 waves (2x2). T3-minimum 2-phase pipeline:
// stage(t+1) issued BEFORE ds_read+MFMA of tile t; one barrier per K-step
// (its vmcnt/lgkm drain guarantees buf[t+1] staged and buf[t] reads done).
// Epilogue: per-wave LDS transpose -> coalesced float4 / uint2 stores.
template <int ACT, int OBF>   // ACT: 0 none, 1 gelu.  OBF: 1 -> bf16 out, 0 -> fp32 out
__global__ __launch_bounds__(256)
void gemm_bt(const u16* __restrict__ A, const u16* __restrict__ B,
             const float* __restrict__ bias, void* __restrict__ Cv,
             int M, int N, int K) {
    __shared__ u16 smem[2][2][128 * 32];   // [buf][A|B][row*32+k] = 32 KiB
    const int tid = threadIdx.x, wv = tid >> 6, ln = tid & 63;
    const int m0 = blockIdx.y * 128, n0 = blockIdx.x * 128;
    const int wm = (wv >> 1) * 64, wn = (wv & 1) * 64;
    const int lo = ln & 15, hi = ln >> 4;
    f32x4 acc[4][4] = {};
    const int r0 = wv * 16 + (ln >> 2);
    const int sl = ln & 3;

    auto stage = [&](int buf, int kt) {
        #pragma unroll
        for (int c = 0; c < 2; ++c) {
            int row = r0 + c * 64;
            int ssl = sl ^ ((row >> 1) & 3);
            int ldsoff = row * 32 + sl * 8;   // elements; = uniform + lane*8 elems
            gload_lds16(A + (size_t)(m0 + row) * K + kt + ssl * 8, (char*)smem[buf][0] + ldsoff * 2);
            gload_lds16(B + (size_t)(n0 + row) * K + kt + ssl * 8, (char*)smem[buf][1] + ldsoff * 2);
        }
    };

    stage(0, 0);
    __syncthreads();
    int cur = 0;
    const int nt = K >> 5;
    for (int t = 0; t < nt; ++t) {
        if (t + 1 < nt) stage(cur ^ 1, (t + 1) * 32);
        bf16x8 af[4], bfr[4];
        #pragma unroll
        for (int i = 0; i < 4; ++i) {
            int row = wm + i * 16 + lo;
            int slot = hi ^ ((row >> 1) & 3);
            af[i] = *(const bf16x8*)(smem[cur][0] + row * 32 + slot * 8);
        }
        #pragma unroll
        for (int j = 0; j < 4; ++j) {
            int row = wn + j * 16 + lo;
            int slot = hi ^ ((row >> 1) & 3);
            bfr[j] = *(const bf16x8*)(smem[cur][1] + row * 32 + slot * 8);
        }
        #pragma unroll
        for (int i = 0; i < 4; ++i)
            #pragma unroll
            for (int j = 0; j < 4; ++j)
                acc[i][j] = __builtin_amdgcn_mfma_f32_16x16x32_bf16(af[i], bfr[j], acc[i][j], 0, 0, 0);
        __syncthreads();
        cur ^= 1;
    }

    // ---- epilogue: transpose 16x64 sub-tiles through LDS, coalesced stores ----
    float* ep = (float*)smem + wv * (16 * 68);   // 4352 B per wave, 17 KiB total
    #pragma unroll
    for (int i = 0; i < 4; ++i) {
        #pragma unroll
        for (int j = 0; j < 4; ++j) {
            int col = n0 + wn + j * 16 + lo;
            float bv = bias[col];
            #pragma unroll
            for (int r = 0; r < 4; ++r) {
                float v = acc[i][j][r] + bv;
                if (ACT == 1) v = gelu_exact(v);
                ep[(hi * 4 + r) * 68 + j * 16 + lo] = v;
            }
        }
        #pragma unroll
        for (int pp = 0; pp < 4; ++pp) {
            int rl = pp * 4 + hi;
            float4 vv = *(const float4*)(ep + rl * 68 + lo * 4);
            size_t row = (size_t)(m0 + wm + i * 16 + rl);
            int col = n0 + wn + lo * 4;
            if (OBF) {
                u16 t4[4] = {f2b(vv.x), f2b(vv.y), f2b(vv.z), f2b(vv.w)};
                *(uint2*)((u16*)Cv + row * N + col) = *(const uint2*)t4;
            } else {
                *(float4*)((float*)Cv + row * N + col) = vv;
            }
        }
    }
}

// ---------- attention v2: flash-style, swapped-operand MFMA ----------
__global__ __launch_bounds__(512)
void attn2_kernel(const u16* __restrict__ qkv, const float* __restrict__ tau,
                  const float* __restrict__ delta, u16* __restrict__ o) {
    __shared__ u16 KL[64 * 64];        // [s][dh], slot16 phys = j ^ (s&7), src pre-swizzled
    __shared__ u16 VT[64 * 72];        // [d][s_l], stride 144B, col-slot16 phys = c ^ ((d>>3)&7)
    __shared__ u16 PL[8][32 * 64];     // per-wave P [q][s], slot16 phys = ls ^ (q&7)
    const int tid = threadIdx.x, w = tid >> 6, ln = tid & 63;
    const int lo = ln & 15, hi = ln >> 4;
    const int qh = blockIdx.x, h = blockIdx.y, b = blockIdx.z;
    const size_t qrow0 = (size_t)b * 512;
    const u16* qp = qkv;
    const u16* kp = qkv + 512;
    const u16* vp = qkv + 1024;
    const int hofs = h * 64;
    const float ts = tau[b] * 0.125f;
    u16* Pw = (u16*)PL[w];
    const int q0 = qh * 256 + w * 32;

    bf16x8 qa[2][2];
    #pragma unroll
    for (int i = 0; i < 2; ++i)
        #pragma unroll
        for (int ks = 0; ks < 2; ++ks)
            qa[i][ks] = *(const bf16x8*)(qp + (qrow0 + q0 + i * 16 + lo) * 1536 + hofs + ks * 32 + hi * 8);

    float m_run[2] = {-1e30f, -1e30f};
    float l_run[2] = {0.f, 0.f};
    f32x4 oacc[2][4] = {};

    const int vsl = tid & 7, vsr = tid >> 3;
    uint4 vreg = *(const uint4*)(vp + (qrow0 + vsr) * 1536 + hofs + vsl * 8);

    for (int nt = 0; nt < 8; ++nt) {
        __syncthreads();
        {
            int s = tid >> 3, j = tid & 7;
            int jl = j ^ (s & 7);
            gload_lds16(kp + (qrow0 + nt * 64 + s) * 1536 + hofs + jl * 8,
                        (char*)KL + tid * 16);
        }
        {
            u16 tmp[8]; *(uint4*)tmp = vreg;
            #pragma unroll
            for (int e = 0; e < 8; ++e) {
                int d = vsl * 8 + e;
                int byt = d * 144 + (((vsr >> 3) ^ vsl) << 4) + (vsr & 7) * 2;
                *(u16*)((char*)VT + byt) = tmp[e];
            }
        }
        if (nt < 7)
            vreg = *(const uint4*)(vp + (qrow0 + (nt + 1) * 64 + vsr) * 1536 + hofs + vsl * 8);
        __syncthreads();

        f32x4 sacc[2][4] = {};
        #pragma unroll
        for (int ks = 0; ks < 2; ++ks) {
            #pragma unroll
            for (int jn = 0; jn < 4; ++jn) {
                int s = jn * 16 + lo;
                int phys = (ks * 4 + hi) ^ (s & 7);
                bf16x8 kb = *(const bf16x8*)((const char*)KL + s * 128 + phys * 16);
                #pragma unroll
                for (int i = 0; i < 2; ++i)
                    sacc[i][jn] = __builtin_amdgcn_mfma_f32_16x16x32_bf16(kb, qa[i][ks], sacc[i][jn], 0, 0, 0);
            }
        }
        float tmax[2] = {-1e30f, -1e30f};
        #pragma unroll
        for (int jn = 0; jn < 4; ++jn) {
            float4 dv4 = *(const float4*)(delta + b * 512 + nt * 64 + jn * 16 + hi * 4);
            float dv[4] = {dv4.x, dv4.y, dv4.z, dv4.w};
            #pragma unroll
            for (int i = 0; i < 2; ++i)
                #pragma unroll
                for (int r = 0; r < 4; ++r) {
                    float v = sacc[i][jn][r] * ts + dv[r] * 0.125f;
                    sacc[i][jn][r] = v;
                    tmax[i] = fmaxf(tmax[i], v);
                }
        }
        #pragma unroll
        for (int i = 0; i < 2; ++i) {
            tmax[i] = fmaxf(tmax[i], __shfl_xor(tmax[i], 16));
            tmax[i] = fmaxf(tmax[i], __shfl_xor(tmax[i], 32));
            float mnew = fmaxf(m_run[i], tmax[i]);
            float fac = __expf(m_run[i] - mnew);
            m_run[i] = mnew;
            l_run[i] *= fac;
            #pragma unroll
            for (int jd = 0; jd < 4; ++jd)
                #pragma unroll
                for (int r = 0; r < 4; ++r) oacc[i][jd][r] *= fac;
        }
        #pragma unroll
        for (int i = 0; i < 2; ++i) {
            float ls = 0.f;
            #pragma unroll
            for (int jn = 0; jn < 4; ++jn) {
                float p0 = __expf(sacc[i][jn][0] - m_run[i]);
                float p1 = __expf(sacc[i][jn][1] - m_run[i]);
                float p2 = __expf(sacc[i][jn][2] - m_run[i]);
                float p3 = __expf(sacc[i][jn][3] - m_run[i]);
                ls += (p0 + p1) + (p2 + p3);
                uint2 pk;
                pk.x = (uint32_t)f2b(p0) | ((uint32_t)f2b(p1) << 16);
                pk.y = (uint32_t)f2b(p2) | ((uint32_t)f2b(p3) << 16);
                int q = i * 16 + lo;
                int ls16 = jn * 2 + (hi >> 1);
                int byt = q * 128 + (((ls16 ^ (q & 7)) << 4)) + (hi & 1) * 8;
                *(uint2*)((char*)Pw + byt) = pk;
            }
            ls += __shfl_xor(ls, 16);
            ls += __shfl_xor(ls, 32);
            l_run[i] += ls;
        }
        #pragma unroll
        for (int ks2 = 0; ks2 < 2; ++ks2) {
            bf16x8 pa[2];
            #pragma unroll
            for (int i = 0; i < 2; ++i) {
                int q = i * 16 + lo;
                int phys = (ks2 * 4 + hi) ^ (q & 7);
                pa[i] = *(const bf16x8*)((const char*)Pw + q * 128 + phys * 16);
            }
            #pragma unroll
            for (int jd = 0; jd < 4; ++jd) {
                int d = jd * 16 + lo;
                int cs = (ks2 * 4 + hi) ^ ((d >> 3) & 7);
                bf16x8 vb = *(const bf16x8*)((const char*)VT + d * 144 + cs * 16);
                #pragma unroll
                for (int i = 0; i < 2; ++i)
                    oacc[i][jd] = __builtin_amdgcn_mfma_f32_16x16x32_bf16(vb, pa[i], oacc[i][jd], 0, 0, 0);
            }
        }
    }
    #pragma unroll
    for (int i = 0; i < 2; ++i) {
        float inv = 1.0f / l_run[i];
        #pragma unroll
        for (int jd = 0; jd < 4; ++jd) {
            u16 t4[4];
            #pragma unroll
            for (int r = 0; r < 4; ++r) t4[r] = f2b(oacc[i][jd][r] * inv);
            size_t row = qrow0 + q0 + i * 16 + lo;
            *(uint2*)(o + row * 512 + hofs + jd * 16 + hi * 4) = *(const uint2*)t4;
        }
    }
}

// ---------- layernorm with residual: x = LN(x + res); writes fp32 + bf16 ----------
__global__ __launch_bounds__(256)
void ln_kernel(const float* __restrict__ xin, const float* __restrict__ res,
               const float* __restrict__ g, const float* __restrict__ bta,
               float* __restrict__ xout, u16* __restrict__ xbf) {
    const int row = blockIdx.x * 4 + (threadIdx.x >> 6);
    const int ln = threadIdx.x & 63;
    const float* xr = xin + (size_t)row * 512;
    const float* rr = res + (size_t)row * 512;
    float4 a = *(const float4*)(xr + ln * 4);
    float4 c = *(const float4*)(xr + 256 + ln * 4);
    float4 ra = *(const float4*)(rr + ln * 4);
    float4 rc = *(const float4*)(rr + 256 + ln * 4);
    a.x += ra.x; a.y += ra.y; a.z += ra.z; a.w += ra.w;
    c.x += rc.x; c.y += rc.y; c.z += rc.z; c.w += rc.w;
    float s = a.x + a.y + a.z + a.w + c.x + c.y + c.z + c.w;
    float sq = a.x*a.x + a.y*a.y + a.z*a.z + a.w*a.w + c.x*c.x + c.y*c.y + c.z*c.z + c.w*c.w;
    #pragma unroll
    for (int m = 1; m < 64; m <<= 1) { s += __shfl_xor(s, m); sq += __shfl_xor(sq, m); }
    float mean = s * 0.001953125f;
    float var = sq * 0.001953125f - mean * mean;
    float rstd = rsqrtf(var + 1e-5f);
    float4 g0 = *(const float4*)(g + ln * 4);
    float4 g1 = *(const float4*)(g + 256 + ln * 4);
    float4 b0 = *(const float4*)(bta + ln * 4);
    float4 b1 = *(const float4*)(bta + 256 + ln * 4);
    float4 o0, o1;
    o0.x = (a.x - mean) * rstd * g0.x + b0.x;
    o0.y = (a.y - mean) * rstd * g0.y + b0.y;
    o0.z = (a.z - mean) * rstd * g0.z + b0.z;
    o0.w = (a.w - mean) * rstd * g0.w + b0.w;
    o1.x = (c.x - mean) * rstd * g1.x + b1.x;
    o1.y = (c.y - mean) * rstd * g1.y + b1.y;
    o1.z = (c.z - mean) * rstd * g1.z + b1.z;
    o1.w = (c.w - mean) * rstd * g1.w + b1.w;
    *(float4*)(xout + (size_t)row * 512 + ln * 4) = o0;
    *(float4*)(xout + (size_t)row * 512 + 256 + ln * 4) = o1;
    u16 t0[4] = {f2b(o0.x), f2b(o0.y), f2b(o0.z), f2b(o0.w)};
    u16 t1[4] = {f2b(o1.x), f2b(o1.y), f2b(o1.z), f2b(o1.w)};
    *(uint2*)(xbf + (size_t)row * 512 + ln * 4) = *(const uint2*)t0;
    *(uint2*)(xbf + (size_t)row * 512 + 256 + ln * 4) = *(const uint2*)t1;
}

// ---------- final LN -> gelu -> * mark -> bf16 ----------
__global__ __launch_bounds__(256)
void lngelu_kernel(const float* __restrict__ xin, const float* __restrict__ g,
                   const float* __restrict__ bta, const float* __restrict__ mark,
                   u16* __restrict__ outb) {
    const int row = blockIdx.x * 4 + (threadIdx.x >> 6);
    const int ln = threadIdx.x & 63;
    const float* xr = xin + (size_t)row * 512;
    float4 a = *(const float4*)(xr + ln * 4);
    float4 c = *(const float4*)(xr + 256 + ln * 4);
    float s = a.x + a.y + a.z + a.w + c.x + c.y + c.z + c.w;
    float sq = a.x*a.x + a.y*a.y + a.z*a.z + a.w*a.w + c.x*c.x + c.y*c.y + c.z*c.z + c.w*c.w;
    #pragma unroll
    for (int m = 1; m < 64; m <<= 1) { s += __shfl_xor(s, m); sq += __shfl_xor(sq, m); }
    float mean = s * 0.001953125f;
    float var = sq * 0.001953125f - mean * mean;
    float rstd = rsqrtf(var + 1e-5f);
    float mk = mark[row];
    float4 g0 = *(const float4*)(g + ln * 4);
    float4 g1 = *(const float4*)(g + 256 + ln * 4);
    float4 b0 = *(const float4*)(bta + ln * 4);
    float4 b1 = *(const float4*)(bta + 256 + ln * 4);
    float v0 = gelu_exact((a.x - mean) * rstd * g0.x + b0.x) * mk;
    float v1 = gelu_exact((a.y - mean) * rstd * g0.y + b0.y) * mk;
    float v2 = gelu_exact((a.z - mean) * rstd * g0.z + b0.z) * mk;
    float v3 = gelu_exact((a.w - mean) * rstd * g0.w + b0.w) * mk;
    float v4 = gelu_exact((c.x - mean) * rstd * g1.x + b1.x) * mk;
    float v5 = gelu_exact((c.y - mean) * rstd * g1.y + b1.y) * mk;
    float v6 = gelu_exact((c.z - mean) * rstd * g1.z + b1.z) * mk;
    float v7 = gelu_exact((c.w - mean) * rstd * g1.w + b1.w) * mk;
    u16 t0[4] = {f2b(v0), f2b(v1), f2b(v2), f2b(v3)};
    u16 t1[4] = {f2b(v4), f2b(v5), f2b(v6), f2b(v7)};
    *(uint2*)(outb + (size_t)row * 512 + ln * 4) = *(const uint2*)t0;
    *(uint2*)(outb + (size_t)row * 512 + 256 + ln * 4) = *(const uint2*)t1;
}

// ---------- final projection: out[32,10] = gb[32,262144] @ pw[10,262144]^T + pb ----------
__global__ __launch_bounds__(256)
void fproj_kernel(const u16* __restrict__ gb, const u16* __restrict__ pw,
                  const float* __restrict__ pb, float* __restrict__ out) {
    __shared__ float red[32][4];
    int n = blockIdx.x, ks = blockIdx.y, tid = threadIdx.x;
    float acc[32];
    #pragma unroll
    for (int m = 0; m < 32; ++m) acc[m] = 0.f;
    for (int j = 0; j < 8; ++j) {
        size_t k0 = (size_t)ks * 16384 + j * 2048 + tid * 8;
        bf16x8 w8 = *(const bf16x8*)(pw + (size_t)n * 262144 + k0);
        float wf[8];
        #pragma unroll
        for (int e = 0; e < 8; ++e) wf[e] = b2f((u16)w8[e]);
        #pragma unroll
        for (int m = 0; m < 32; ++m) {
            bf16x8 g8 = *(const bf16x8*)(gb + (size_t)m * 262144 + k0);
            float a = acc[m];
            #pragma unroll
            for (int e = 0; e < 8; ++e) a += b2f((u16)g8[e]) * wf[e];
            acc[m] = a;
        }
    }
    int w = tid >> 6;
    #pragma unroll
    for (int m = 0; m < 32; ++m) {
        float s = acc[m];
        s += __shfl_xor(s, 1);  s += __shfl_xor(s, 2);  s += __shfl_xor(s, 4);
        s += __shfl_xor(s, 8);  s += __shfl_xor(s, 16); s += __shfl_xor(s, 32);
        if ((tid & 63) == 0) red[m][w] = s;
    }
    __syncthreads();
    if (tid < 32) {
        int m = tid;
        float s = red[m][0] + red[m][1] + red[m][2] + red[m][3];
        if (ks == 0) s += pb[n];
        atomicAdd(&out[m * 10 + n], s);
    }
}

// =================== host ===================
extern "C" void kernel_launch(void* const* d_in, const int* in_sizes, int n_in,
                              void* d_out, int out_size, void* d_ws, size_t ws_size,
                              hipStream_t stream) {
    const float* x_enc  = (const float*)d_in[0];
    const float* x_mark = (const float*)d_in[1];
    const float* tok_w  = (const float*)d_in[2];
    const float* Wq = (const float*)d_in[3];   const float* bq = (const float*)d_in[4];
    const float* Wk = (const float*)d_in[5];   const float* bk = (const float*)d_in[6];
    const float* Wv = (const float*)d_in[7];   const float* bv = (const float*)d_in[8];
    const float* Wo = (const float*)d_in[9];   const float* bo = (const float*)d_in[10];
    const float* W1 = (const float*)d_in[11];  const float* b1 = (const float*)d_in[12];
    const float* W2 = (const float*)d_in[13];  const float* b2 = (const float*)d_in[14];
    const float* ln1_g = (const float*)d_in[15]; const float* ln1_b = (const float*)d_in[16];
    const float* ln2_g = (const float*)d_in[17]; const float* ln2_b = (const float*)d_in[18];
    const float* norm_g = (const float*)d_in[19]; const float* norm_b = (const float*)d_in[20];
    const float* proj_w = (const float*)d_in[21]; const float* proj_b = (const float*)d_in[22];
    const float* tau_cw = (const float*)d_in[23];
    const float* tau_w0 = (const float*)d_in[24]; const float* tau_b0 = (const float*)d_in[25];
    const float* tau_w1 = (const float*)d_in[26]; const float* tau_b1 = (const float*)d_in[27];
    const float* tau_w2 = (const float*)d_in[28];
    const float* del_cw = (const float*)d_in[29];
    const float* del_w0 = (const float*)d_in[30]; const float* del_b0 = (const float*)d_in[31];
    const float* del_w1 = (const float*)d_in[32]; const float* del_b1 = (const float*)d_in[33];
    const float* del_w2 = (const float*)d_in[34];
    float* out = (float*)d_out;

    char* ws = (char*)d_ws;
    size_t off = 0;
    auto alloc = [&](size_t bytes) -> void* {
        void* p = ws + off;
        off += (bytes + 255) & ~(size_t)255;
        return p;
    };
    u16* wqkvb = (u16*)alloc((size_t)3 * 786432 * 2);   // per layer [1536][512]
    u16* wob = (u16*)alloc(786432 * 2);
    u16* w1b = (u16*)alloc(3145728 * 2);
    u16* w2b = (u16*)alloc(3145728 * 2);
    u16* pwb = (u16*)alloc(2621440 * 2);
    float* bqkvb = (float*)alloc(3 * 1536 * 4);
    float* petab = (float*)alloc((size_t)262144 * 4);
    float* meanb = (float*)alloc(512 * 4);
    float* stdb  = (float*)alloc(512 * 4);
    float* taub  = (float*)alloc(32 * 4);
    float* delb  = (float*)alloc(16384 * 4);
    float* xf = (float*)alloc((size_t)8388608 * 4);
    u16*  xb  = (u16*)alloc((size_t)8388608 * 2);
    float* sf = (float*)alloc((size_t)8388608 * 4);
    u16* qkvb = (u16*)alloc((size_t)16384 * 1536 * 2);  // 50.3MB
    u16* ob   = (u16*)alloc((size_t)8388608 * 2);       // 16.8MB
    u16* hb   = qkvb;   // FFN hidden (16384x2048 bf16 = 64MB) overlays qkvb+ob (67MB)
    u16* gbuf = qkvb;   // final gelu buffer overlays too

    auto cvt = [&](const float* src, u16* dst, int n) {
        f2b_kernel<<<dim3((n + 2047) / 2048), dim3(256), 0, stream>>>(src, dst, n);
    };
    for (int i = 0; i < 3; ++i) {
        cvt(Wq + (size_t)i * 262144, wqkvb + (size_t)i * 786432 + 0,      262144);
        cvt(Wk + (size_t)i * 262144, wqkvb + (size_t)i * 786432 + 262144, 262144);
        cvt(Wv + (size_t)i * 262144, wqkvb + (size_t)i * 786432 + 524288, 262144);
    }
    cvt(Wo, wob, 786432);
    cvt(W1, w1b, 3145728); cvt(W2, w2b, 3145728);
    cvt(proj_w, pwb, 2621440);
    packb_kernel<<<dim3(18), dim3(256), 0, stream>>>(bq, bk, bv, bqkvb);
    pe_kernel<<<dim3(512), dim3(256), 0, stream>>>(petab);

    stats_kernel<<<dim3(32), dim3(64), 0, stream>>>(x_enc, meanb, stdb);
    proj_kernel<<<dim3(32), dim3(128), 0, stream>>>(x_enc, stdb, tau_cw, tau_w0, tau_b0,
                                                    tau_w1, tau_b1, tau_w2, taub, 1, 1);
    proj_kernel<<<dim3(32), dim3(128), 0, stream>>>(x_enc, meanb, del_cw, del_w0, del_b0,
                                                    del_w1, del_b1, del_w2, delb, 512, 0);
    tokconv_kernel<<<dim3(16, 32), dim3(256), 0, stream>>>(x_enc, tok_w, petab, xf, xb);

    for (int i = 0; i < 3; ++i) {
        const u16* wqkv_i = wqkvb + (size_t)i * 786432;
        const u16* wo_i = wob + (size_t)i * 262144;
        const u16* w1_i = w1b + (size_t)i * 1048576;
        const u16* w2_i = w2b + (size_t)i * 1048576;
        gemm_bt<0, 1><<<dim3(12, 128), dim3(256), 0, stream>>>(xb, wqkv_i, bqkvb + i * 1536, qkvb, 16384, 1536, 512);
        attn2_kernel<<<dim3(2, 8, 32), dim3(512), 0, stream>>>(qkvb, taub, delb, ob);
        gemm_bt<0, 0><<<dim3(4, 128), dim3(256), 0, stream>>>(ob, wo_i, bo + i * 512, sf, 16384, 512, 512);
        ln_kernel<<<dim3(4096), dim3(256), 0, stream>>>(xf, sf, ln1_g + i * 512, ln1_b + i * 512, xf, xb);
        gemm_bt<1, 1><<<dim3(16, 128), dim3(256), 0, stream>>>(xb, w1_i, b1 + i * 2048, hb, 16384, 2048, 512);
        gemm_bt<0, 0><<<dim3(4, 128), dim3(256), 0, stream>>>(hb, w2_i, b2 + i * 512, sf, 16384, 512, 2048);
        ln_kernel<<<dim3(4096), dim3(256), 0, stream>>>(xf, sf, ln2_g + i * 512, ln2_b + i * 512, xf, xb);
    }

    lngelu_kernel<<<dim3(4096), dim3(256), 0, stream>>>(xf, norm_g, norm_b, x_mark, gbuf);
    hipMemsetAsync(d_out, 0, (size_t)out_size * 4, stream);
    fproj_kernel<<<dim3(10, 16), dim3(256), 0, stream>>>(gbuf, pwb, proj_b, out);
}